// Round 14
// baseline (478.341 us; speedup 1.0000x reference)
//
#include <hip/hip_runtime.h>

#define TT   1024
#define NR   36          // 32-col dirs records per band-row (skew o up to 126)
#define NWP  18          // 32-step phases per wave (2 records = 64 cols each)
#define NPH  (NWP + 21)  // + 3*(8 waves - 1) pipeline lag
#define FINF 1e30f

template<bool A> struct BoolC { static constexpr bool value = A; };

// dirs layout (bit format as baseline, keyed by 64-row band):
//   uint2 {ne2_mask, diag_mask} at ((b*16+bi)*NR + T)*64 + rr
//   bit k of record T = col 32T - o + k, o = 2 * skew-lane of row rr:
//   o = 2*((bi&1)*32 + (rr>>1))  [8 waves x 128 rows, 2 rows/lane, slope-2:
//   lane L computes cols 2(s-L), 2(s-L)+1 each step -> 576 steps not 1088]
// ne2: dir != left. diag: dir == diag (first-min argmin).

__device__ __forceinline__ float dpp_shr1_old(float oldv, float x) {
    return __int_as_float(__builtin_amdgcn_update_dpp(
        __float_as_int(oldv), __float_as_int(x), 0x138, 0xF, 0xF, false));
}

// ---------------- K1: forward DP, slope-2 (2 cols/step, 4 cells/lane-step) --
// Wave w owns rows 128w..128w+127; lane L rows 128w+2L,+2L+1. At step s lane L
// computes cols c0=2(s-L), c1=c0+1. Cross-lane: lane L-1's row1 pair at step
// s-1 is exactly (c0,c1) -> 2 DPP shifts/step; diag@c0-1 = previous uB.
// Lag-3 barrier pipeline: wave w runs phase P=G-3w (32 steps, records 2P,2P+1);
// producer completed P+2 -> published cols <= 64P+65 = consumer's last DPP
// prefetch. q split even/odd in LDS so stride-2 reads stay 2-way (free).
// ACT peel P<2 (s<64); (0,0) via ba>9e29 clamp. Halves of 16 steps bound VGPR.
__global__ __launch_bounds__(512, 2) void dtw_forward(
    const float* __restrict__ preds,
    const float* __restrict__ targs,
    uint2* __restrict__ dirs)
{
    __shared__ float2 qsh[2][512];      // [col&1][col>>1]
    __shared__ float  mbox[7][TT];

    const int tid  = threadIdx.x;
    const int w    = tid >> 6;
    const int lane = tid & 63;
    const int b    = blockIdx.x;

    for (int k = tid; k < TT; k += 512) {
        float4 t4 = ((const float4*)targs)[(size_t)b * TT + k];
        qsh[k & 1][k >> 1] = make_float2(t4.x, t4.y);
    }
    for (int k = tid; k < 7 * TT; k += 512) ((float*)mbox)[k] = FINF;

    float px0, py0, px1, py1;
    {
        const int row0 = w * 128 + 2 * lane;
        float4 pv = ((const float4*)preds)[(size_t)b * TT + row0];
        px0 = pv.x; py0 = pv.y;
        float4 pw2 = ((const float4*)preds)[(size_t)b * TT + row0 + 1];
        px1 = pw2.x; py1 = pw2.y;
    }
    __syncthreads();

    const float* src = (w > 0) ? mbox[w - 1] : nullptr;
    float*       dst = (w < 7) ? mbox[w]     : nullptr;

    float cur01 = FINF, cur11 = FINF;          // own rows' col c1 values
    float uA = FINF, uB = FINF, uBp = FINF;    // up row @ c0, c1, c0-1
    unsigned pA0 = 0, pA1 = 0, pA2 = 0, pA3 = 0;   // deferred record 2P
    unsigned pB0 = 0, pB1 = 0, pB2 = 0, pB3 = 0;   // deferred record 2P+1
    int pP = -1;

    const int bi  = 2 * w + (lane >> 5);
    const int rr0 = 2 * (lane & 31);
    const bool is63 = (lane == 63);

    // one 16-step half = one 32-col dirs record
    auto runHalf = [&](int T, unsigned& o0, unsigned& o1, unsigned& o2,
                       unsigned& o3, auto actc) {
        constexpr bool ACT = decltype(actc)::value;
        float bnd[34];                 // src cols 32T..32T+33 (33,34 = prefetch)
#pragma unroll
        for (int i = 0; i < 34; ++i) bnd[i] = FINF;
        if (w > 0) {
#pragma unroll
            for (int i = 0; i < 34; ++i) {
                const int c = 32 * T + i;
                if (c < TT) bnd[i] = src[c];
            }
        }
        if (T == 0) { uA = bnd[0]; uB = bnd[1]; }   // first-step up pair
        float2 qa[16], qb[16];
#pragma unroll
        for (int k = 0; k < 16; ++k) {
            const int m = (16 * T + k - lane) & 511;   // c0 = 2m
            qa[k] = qsh[0][m];
            qb[k] = qsh[1][m];
        }
        float2 bq[16];
        unsigned au0 = 0, ad0 = 0, au1 = 0, ad1 = 0;
#pragma unroll
        for (int k = 0; k < 16; ++k) {
            const float dxa0 = px0 - qa[k].x, dya0 = py0 - qa[k].y;
            const float d00 = __builtin_amdgcn_sqrtf(dxa0 * dxa0 + dya0 * dya0);
            const float dxb0 = px0 - qb[k].x, dyb0 = py0 - qb[k].y;
            const float d01 = __builtin_amdgcn_sqrtf(dxb0 * dxb0 + dyb0 * dyb0);
            const float dxa1 = px1 - qa[k].x, dya1 = py1 - qa[k].y;
            const float d10 = __builtin_amdgcn_sqrtf(dxa1 * dxa1 + dya1 * dya1);
            const float dxb1 = px1 - qb[k].x, dyb1 = py1 - qb[k].y;
            const float d11 = __builtin_amdgcn_sqrtf(dxb1 * dxb1 + dyb1 * dyb1);

            // v00 (r0,c0): cu=uA cd=uBp cl=cur01
            float ba00 = fminf(fminf(uA, cur01), uBp);
            const unsigned bd00 = (uBp == ba00) ? 1u : 0u;
            const unsigned bu00 = ((uA <= cur01) ? 1u : 0u) | bd00;
            if constexpr (ACT) ba00 = (ba00 > 9e29f) ? 0.0f : ba00;
            const float v00 = d00 + ba00;
            // v01 (r0,c1): cu=uB cd=uA cl=v00
            const float ba01 = fminf(fminf(uB, v00), uA);
            const unsigned bd01 = (uA == ba01) ? 1u : 0u;
            const unsigned bu01 = ((uB <= v00) ? 1u : 0u) | bd01;
            const float v01 = d01 + ba01;
            // v10 (r1,c0): cu=v00 cd=cur01(old) cl=cur11(old)
            const float ba10 = fminf(fminf(v00, cur11), cur01);
            const unsigned bd10 = (cur01 == ba10) ? 1u : 0u;
            const unsigned bu10 = ((v00 <= cur11) ? 1u : 0u) | bd10;
            const float v10 = d10 + ba10;
            // v11 (r1,c1): cu=v01 cd=v00 cl=v10
            const float ba11 = fminf(fminf(v01, v10), v00);
            const unsigned bd11 = (v00 == ba11) ? 1u : 0u;
            const unsigned bu11 = ((v01 <= v10) ? 1u : 0u) | bd11;
            const float v11 = d11 + ba11;

            au0 = (au0 << 2) | (bu00 << 1) | bu01;
            ad0 = (ad0 << 2) | (bd00 << 1) | bd01;
            au1 = (au1 << 2) | (bu10 << 1) | bu11;
            ad1 = (ad1 << 2) | (bd10 << 1) | bd11;

            float sv10, sv11;
            if constexpr (ACT) {
                const bool act = (lane <= 16 * T + k);
                cur01 = act ? v01 : cur01;
                cur11 = act ? v11 : cur11;
                sv10 = act ? v10 : FINF;
                sv11 = act ? v11 : FINF;
            } else {
                cur01 = v01; cur11 = v11;
                sv10 = v10;  sv11 = v11;
            }
            bq[k] = make_float2(sv10, sv11);
            // next step's up values: lane0 <- src cols 2(s+1), 2(s+1)+1
            uBp = uB;
            uA = dpp_shr1_old(bnd[2 * k + 2], sv10);
            uB = dpp_shr1_old(bnd[2 * k + 3], sv11);
        }
        // batched boundary publish (row 128w+127 pairs; barrier orders it)
        if (is63 && w < 7) {
#pragma unroll
            for (int k = 0; k < 16; ++k) {
                const int c = 32 * T + 2 * k - 126;   // even
                if ((unsigned)c < 1024u) *(float2*)&dst[c] = bq[k];
            }
        }
        o0 = au0; o1 = ad0; o2 = au1; o3 = ad1;
    };

    for (int G = 0; G < NPH; ++G) {
        // deferred dirs stores for the previous phase (post-barrier)
        if (pP >= 0) {
            const size_t base = (size_t)((b * 16 + bi) * NR + 2 * pP) * 64 + rr0;
            *(uint4*)&dirs[base] = make_uint4(
                __builtin_bitreverse32(pA0), __builtin_bitreverse32(pA1),
                __builtin_bitreverse32(pA2), __builtin_bitreverse32(pA3));
            *(uint4*)&dirs[base + 64] = make_uint4(
                __builtin_bitreverse32(pB0), __builtin_bitreverse32(pB1),
                __builtin_bitreverse32(pB2), __builtin_bitreverse32(pB3));
            pP = -1;
        }
        const int P = G - 3 * w;             // wave-uniform phase index
        if ((unsigned)P < (unsigned)NWP) {
            if (P < 2) {
                runHalf(2 * P,     pA0, pA1, pA2, pA3, BoolC<true>{});
                runHalf(2 * P + 1, pB0, pB1, pB2, pB3, BoolC<true>{});
            } else {
                runHalf(2 * P,     pA0, pA1, pA2, pA3, BoolC<false>{});
                runHalf(2 * P + 1, pB0, pB1, pB2, pB3, BoolC<false>{});
            }
            pP = P;
        }
        __syncthreads();
    }
    if (pP >= 0) {
        const size_t base = (size_t)((b * 16 + bi) * NR + 2 * pP) * 64 + rr0;
        *(uint4*)&dirs[base] = make_uint4(
            __builtin_bitreverse32(pA0), __builtin_bitreverse32(pA1),
            __builtin_bitreverse32(pA2), __builtin_bitreverse32(pA3));
        *(uint4*)&dirs[base + 64] = make_uint4(
            __builtin_bitreverse32(pB0), __builtin_bitreverse32(pB1),
            __builtin_bitreverse32(pB2), __builtin_bitreverse32(pB3));
    }
}

// ---------------- K2: exit-only per-band walk, O(1) row-step ----------------
__global__ __launch_bounds__(1024) void dtw_exits(
    const uint2* __restrict__ dirs,
    unsigned short* __restrict__ exitc)
{
    __shared__ uint2 raw[NR * 64];
    __shared__ unsigned nebit[64][32];
    __shared__ unsigned dgbit[64][32];
    __shared__ short prevnz[64][32];

    const int tid = threadIdx.x;
    const int b = blockIdx.x >> 4, bi = blockIdx.x & 15;

    for (int i = tid; i < NR * 64; i += 1024)
        raw[i] = dirs[(size_t)(b * 16 + bi) * (NR * 64) + i];
    __syncthreads();
    for (int i = tid; i < 64 * 32; i += 1024) {
        const int rr = i >> 5, u = i & 31;
        const int o  = (((bi & 1) << 5) + (rr >> 1)) << 1;   // slope-2 skew
        const int T0 = u + (o >> 5), sh = o & 31;
        uint2 A  = raw[T0 * 64 + rr];
        uint2 Bv = raw[(T0 + 1) * 64 + rr];
        nebit[rr][u] = sh ? ((A.x >> sh) | (Bv.x << (32 - sh))) : A.x;
        dgbit[rr][u] = sh ? ((A.y >> sh) | (Bv.y << (32 - sh))) : A.y;
    }
    __syncthreads();
    if (tid < 64) {               // per-row prev-nonzero-word table
        int p = -1;
        for (int u = 0; u < 32; ++u) {
            if (nebit[tid][u] != 0u) p = u;
            prevnz[tid][u] = (short)p;
        }
    }
    __syncthreads();

    int j = tid;
    for (int rr = 63; rr >= 0; --rr) {
        if (bi == 0 && rr == 0) { j = 0; break; }
        const int u = j >> 5, m = j & 31;
        const unsigned wv = nebit[rr][u] << (31 - m);
        int j2;
        if (wv != 0u) j2 = (u << 5) + m - __builtin_clz(wv);
        else {
            const int u2 = (u > 0) ? (int)prevnz[rr][u - 1] : -1;
            j2 = (u2 < 0) ? 0 : ((u2 << 5) + 31 - __builtin_clz(nebit[rr][u2]));
        }
        const int diag = (int)((dgbit[rr][j2 >> 5] >> (j2 & 31)) & 1u);
        j = j2 - diag;
        if (j < 0) j = 0;   // safety net (unreachable on correct dirs)
    }
    exitc[((size_t)(b * 16 + bi) << 10) + tid] = (unsigned short)j;
}

// ---------------- K3: loss replay (stitch folded in, O(1) row-step) --------
__global__ __launch_bounds__(64) void dtw_loss(
    const float* __restrict__ preds,
    const float* __restrict__ targs,
    const float* __restrict__ subcoef,
    const uint2* __restrict__ dirs,
    const unsigned short* __restrict__ exitc,
    float* __restrict__ out)
{
    __shared__ uint2 raw[NR * 64];
    __shared__ unsigned nebit[64][32];
    __shared__ unsigned dgbit[64][32];
    __shared__ short prevnz[64][32];
    __shared__ float2 qsh[TT];
    __shared__ float2 psh[64];
    __shared__ unsigned recs[160];

    const int lane = threadIdx.x;
    const int b = blockIdx.x >> 4, bi = blockIdx.x & 15;

    for (int i = lane; i < NR * 64; i += 64)
        raw[i] = dirs[(size_t)(b * 16 + bi) * (NR * 64) + i];
    for (int k = lane; k < TT; k += 64) {
        float4 t4 = ((const float4*)targs)[(size_t)b * TT + k];
        qsh[k] = make_float2(t4.x, t4.y);
    }
    {
        float4 p4 = ((const float4*)preds)[(size_t)b * TT + bi * 64 + lane];
        psh[lane] = make_float2(p4.x, p4.y);
    }
    __syncthreads();
    for (int i = lane; i < 64 * 32; i += 64) {
        const int rr = i >> 5, u = i & 31;
        const int o  = (((bi & 1) << 5) + (rr >> 1)) << 1;   // slope-2 skew
        const int T0 = u + (o >> 5), sh = o & 31;
        uint2 A  = raw[T0 * 64 + rr];
        uint2 Bv = raw[(T0 + 1) * 64 + rr];
        nebit[rr][u] = sh ? ((A.x >> sh) | (Bv.x << (32 - sh))) : A.x;
        dgbit[rr][u] = sh ? ((A.y >> sh) | (Bv.y << (32 - sh))) : A.y;
    }
    __syncthreads();
    {                              // per-row prev-nonzero-word table (row=lane)
        int p = -1;
        for (int u = 0; u < 32; ++u) {
            if (nebit[lane][u] != 0u) p = u;
            prevnz[lane][u] = (short)p;
        }
    }

    // entry col for this band: fold of exitc over bands 15..bi+1
    int j = TT - 1;
    for (int k = 15; k > bi; --k)
        j = exitc[((size_t)(b * 16 + k) << 10) + j];
    __syncthreads();

    // wave-redundant replay; lane 0 records <=32-col span chunks
    int nrec = 0;
    for (int rr = 63; rr >= 0; --rr) {
        int j2;
        if (bi == 0 && rr == 0) j2 = 0;
        else {
            const int u = j >> 5, m = j & 31;
            const unsigned wv = nebit[rr][u] << (31 - m);
            if (wv != 0u) j2 = (u << 5) + m - __builtin_clz(wv);
            else {
                const int u2 = (u > 0) ? (int)prevnz[rr][u - 1] : -1;
                j2 = (u2 < 0) ? 0 : ((u2 << 5) + 31 - __builtin_clz(nebit[rr][u2]));
            }
        }
        int c = j;
        for (;;) {
            int cl = (c - 31 > j2) ? (c - 31) : j2;
            if (lane == 0)
                recs[nrec] = ((unsigned)rr << 20) | ((unsigned)cl << 10) | (unsigned)c;
            ++nrec;
            if (cl == j2) break;
            c = cl - 1;
        }
        if (bi == 0 && rr == 0) j = 0;
        else {
            const int diag = (int)((dgbit[rr][j2 >> 5] >> (j2 & 31)) & 1u);
            j = j2 - diag;
            if (j < 0) j = 0;   // safety net (unreachable on correct dirs)
        }
    }
    __syncthreads();

    const float sc0 = subcoef[0], sc1 = subcoef[1];
    float acc = 0.0f;
    for (int k = lane; k < nrec; k += 64) {
        unsigned rec = recs[k];
        int rr = (int)(rec >> 20), cl = (int)((rec >> 10) & 1023u), ch = (int)(rec & 1023u);
        float2 p = psh[rr];
        for (int c = cl; c <= ch; ++c) {
            float2 q = qsh[c];
            acc += fabsf(p.x - q.x) * sc0 + fabsf(p.y - q.y) * sc1;
        }
    }
    for (int o = 32; o; o >>= 1) acc += __shfl_down(acc, o);
    if (lane == 0) atomicAdd(out, acc);
}

extern "C" void kernel_launch(void* const* d_in, const int* in_sizes, int n_in,
                              void* d_out, int out_size, void* d_ws, size_t ws_size,
                              hipStream_t stream)
{
    const float* preds   = (const float*)d_in[0];
    const float* targs   = (const float*)d_in[1];
    const float* subcoef = (const float*)d_in[2];
    float* out = (float*)d_out;

    const int B = in_sizes[0] / (TT * 4);

    const size_t dirsBytes = (size_t)B * 16 * NR * 64 * sizeof(uint2);        // ~18.9 MB
    uint2* dirs = (uint2*)d_ws;
    unsigned short* exitc = (unsigned short*)((char*)d_ws + dirsBytes);       // 2 MB

    hipMemsetAsync(out, 0, sizeof(float), stream);
    dtw_forward<<<dim3(B), dim3(512), 0, stream>>>(preds, targs, dirs);
    dtw_exits<<<dim3(B * 16), dim3(1024), 0, stream>>>(dirs, exitc);
    dtw_loss<<<dim3(B * 16), dim3(64), 0, stream>>>(preds, targs, subcoef, dirs, exitc, out);
}

// Round 15
// 404.088 us; speedup vs baseline: 1.1838x; 1.1838x over previous
//
#include <hip/hip_runtime.h>

#define TT   1024
#define NW   34          // 32-step windows; slope-1 skew offset up to 63
#define NPH  (NW + 21)   // barrier pipeline phases: NW + 3*(8 waves - 1)
#define FINF 1e30f

template<bool A> struct BoolC { static constexpr bool value = A; };

// dirs layout (bit format as baseline, keyed by 64-row band):
//   uint2 {ne2_mask, diag_mask} at ((b*16+bi)*NW + T)*64 + rr
//   bit k of window T = col 32T - o + k, o = skew lane of row rr:
//   o = (bi&1)*32 + (rr>>1)  [8 waves x 128 rows, 2 rows/lane, slope-1]
// ne2: dir != left. diag: dir == diag (first-min argmin).

__device__ __forceinline__ float dpp_shr1_old(float oldv, float x) {
    return __int_as_float(__builtin_amdgcn_update_dpp(
        __float_as_int(oldv), __float_as_int(x), 0x138, 0xF, 0xF, false));
}

// ---------------- K1: forward DP (r6-verified body, 233us) ------------------
__global__ __launch_bounds__(512) void dtw_forward(
    const float* __restrict__ preds,
    const float* __restrict__ targs,
    uint2* __restrict__ dirs)
{
    __shared__ float2 qsh[TT];
    __shared__ float  mbox[7][TT];

    const int tid  = threadIdx.x;
    const int w    = tid >> 6;
    const int lane = tid & 63;
    const int b    = blockIdx.x;

    for (int k = tid; k < TT; k += 512) {
        float4 t4 = ((const float4*)targs)[(size_t)b * TT + k];
        qsh[k] = make_float2(t4.x, t4.y);
    }
    for (int k = tid; k < 7 * TT; k += 512) ((float*)mbox)[k] = FINF;

    float px0, py0, px1, py1;
    {
        const int row0 = w * 128 + 2 * lane;
        float4 pv = ((const float4*)preds)[(size_t)b * TT + row0];
        px0 = pv.x; py0 = pv.y;
        float4 pw = ((const float4*)preds)[(size_t)b * TT + row0 + 1];
        px1 = pw.x; py1 = pw.y;
    }
    __syncthreads();

    const float* src = (w > 0) ? mbox[w - 1] : nullptr;
    float*       dst = (w < 7) ? mbox[w]     : nullptr;

    float cur0 = FINF, cur1 = FINF, uprev = FINF, ucur = FINF;
    unsigned au0 = 0, ad0 = 0, au1 = 0, ad1 = 0;
    unsigned pau0 = 0, pad0 = 0, pau1 = 0, pad1 = 0;
    int pT = -1;

    const int bi  = 2 * w + (lane >> 5);
    const int rr0 = 2 * (lane & 31);
    const bool is63 = (lane == 63);

    for (int G = 0; G < NPH; ++G) {
        if (pT >= 0) {
            const size_t base = (size_t)((b * 16 + bi) * NW + pT) * 64 + rr0;
            *(uint4*)&dirs[base] =
                make_uint4(__builtin_bitreverse32(pau0), __builtin_bitreverse32(pad0),
                           __builtin_bitreverse32(pau1), __builtin_bitreverse32(pad1));
            pT = -1;
        }
        const int T = G - 3 * w;
        if ((unsigned)T < (unsigned)NW) {
            float bnd[33];
#pragma unroll
            for (int k = 0; k < 33; ++k) bnd[k] = FINF;
            if (w > 0) {
#pragma unroll
                for (int k = 0; k < 33; ++k) {
                    const int c = 32 * T + k;
                    if (c < TT) bnd[k] = src[c];
                }
            }
            if (T == 0) ucur = bnd[0];
            float qx[32], qy[32];
#pragma unroll
            for (int k = 0; k < 32; ++k) {
                float2 v = qsh[(32 * T + k - lane) & (TT - 1)];
                qx[k] = v.x; qy[k] = v.y;
            }
            float bq[32];
            auto body = [&](auto actc) {
                constexpr bool ACT = decltype(actc)::value;
#pragma unroll
                for (int k2 = 0; k2 < 32; ++k2) {
                    const int s = 32 * T + k2;
                    const float dx0 = px0 - qx[k2], dy0 = py0 - qy[k2];
                    const float d0 = __builtin_amdgcn_sqrtf(dx0 * dx0 + dy0 * dy0);
                    const float dx1 = px1 - qx[k2], dy1 = py1 - qy[k2];
                    const float d1 = __builtin_amdgcn_sqrtf(dx1 * dx1 + dy1 * dy1);

                    const float u = ucur;
                    float ba0 = fminf(fminf(u, cur0), uprev);
                    const unsigned bd0 = (uprev == ba0) ? 1u : 0u;
                    const unsigned bu0 = ((u <= cur0) ? 1u : 0u) | bd0;
                    if constexpr (ACT) ba0 = (ba0 > 9e29f) ? 0.0f : ba0;
                    const float v0 = d0 + ba0;
                    const float ba1 = fminf(fminf(v0, cur1), cur0);
                    const unsigned bd1 = (cur0 == ba1) ? 1u : 0u;
                    const unsigned bu1 = ((v0 <= cur1) ? 1u : 0u) | bd1;
                    const float v1 = d1 + ba1;

                    au0 = au0 + au0 + bu0;  ad0 = ad0 + ad0 + bd0;
                    au1 = au1 + au1 + bu1;  ad1 = ad1 + ad1 + bd1;

                    if constexpr (ACT) {
                        const bool act = (lane <= s);
                        cur0 = act ? v0 : cur0;
                        cur1 = act ? v1 : cur1;
                    } else {
                        cur0 = v0; cur1 = v1;
                    }
                    uprev = u;
                    bq[k2] = cur1;
                    ucur = dpp_shr1_old(bnd[k2 + 1], cur1);
                }
            };
            if (T < 2) body(BoolC<true>{}); else body(BoolC<false>{});

            if (is63 && w < 7) {
#pragma unroll
                for (int k2 = 0; k2 < 32; ++k2) {
                    const int c = 32 * T + k2 - 63;
                    if ((unsigned)c < 1024u) dst[c] = bq[k2];
                }
            }
            pau0 = au0; pad0 = ad0; pau1 = au1; pad1 = ad1; pT = T;
            au0 = ad0 = au1 = ad1 = 0u;
        }
        __syncthreads();
    }
    if (pT >= 0) {
        const size_t base = (size_t)((b * 16 + bi) * NW + pT) * 64 + rr0;
        *(uint4*)&dirs[base] =
            make_uint4(__builtin_bitreverse32(pau0), __builtin_bitreverse32(pad0),
                       __builtin_bitreverse32(pau1), __builtin_bitreverse32(pad1));
    }
}

// ---------------- K2: exit-only per-band walk, O(1) row-step ----------------
// prevnz[rr][u] = largest u' <= u with nebit[rr][u'] != 0 (else -1) turns the
// divergent while-scan into a constant-cost lookup (wave row-step = max over
// lanes was heavy-tailed on long left-runs).
__global__ __launch_bounds__(1024) void dtw_exits(
    const uint2* __restrict__ dirs,
    unsigned short* __restrict__ exitc)
{
    __shared__ uint2 raw[NW * 64];
    __shared__ unsigned nebit[64][32];
    __shared__ unsigned dgbit[64][32];
    __shared__ short prevnz[64][32];

    const int tid = threadIdx.x;
    const int b = blockIdx.x >> 4, bi = blockIdx.x & 15;

    for (int i = tid; i < NW * 64; i += 1024)
        raw[i] = dirs[(size_t)(b * 16 + bi) * (NW * 64) + i];
    __syncthreads();
    for (int i = tid; i < 64 * 32; i += 1024) {
        const int rr = i >> 5, u = i & 31;
        const int o  = ((bi & 1) << 5) + (rr >> 1);
        const int T0 = u + (o >> 5), sh = o & 31;
        uint2 A  = raw[T0 * 64 + rr];
        uint2 Bv = raw[(T0 + 1) * 64 + rr];
        nebit[rr][u] = sh ? ((A.x >> sh) | (Bv.x << (32 - sh))) : A.x;
        dgbit[rr][u] = sh ? ((A.y >> sh) | (Bv.y << (32 - sh))) : A.y;
    }
    __syncthreads();
    if (tid < 64) {               // per-row prev-nonzero-word table
        int p = -1;
        for (int u = 0; u < 32; ++u) {
            if (nebit[tid][u] != 0u) p = u;
            prevnz[tid][u] = (short)p;
        }
    }
    __syncthreads();

    int j = tid;
    for (int rr = 63; rr >= 0; --rr) {
        if (bi == 0 && rr == 0) { j = 0; break; }
        const int u = j >> 5, m = j & 31;
        const unsigned wv = nebit[rr][u] << (31 - m);
        int j2;
        if (wv != 0u) j2 = (u << 5) + m - __builtin_clz(wv);
        else {
            const int u2 = (u > 0) ? (int)prevnz[rr][u - 1] : -1;
            j2 = (u2 < 0) ? 0 : ((u2 << 5) + 31 - __builtin_clz(nebit[rr][u2]));
        }
        const int diag = (int)((dgbit[rr][j2 >> 5] >> (j2 & 31)) & 1u);
        j = j2 - diag;
        if (j < 0) j = 0;   // safety net (unreachable on correct dirs)
    }
    exitc[((size_t)(b * 16 + bi) << 10) + tid] = (unsigned short)j;
}

// ---------------- K3: loss replay (stitch folded in, O(1) row-step) --------
__global__ __launch_bounds__(64) void dtw_loss(
    const float* __restrict__ preds,
    const float* __restrict__ targs,
    const float* __restrict__ subcoef,
    const uint2* __restrict__ dirs,
    const unsigned short* __restrict__ exitc,
    float* __restrict__ out)
{
    __shared__ uint2 raw[NW * 64];
    __shared__ unsigned nebit[64][32];
    __shared__ unsigned dgbit[64][32];
    __shared__ short prevnz[64][32];
    __shared__ float2 qsh[TT];
    __shared__ float2 psh[64];
    __shared__ unsigned recs[160];

    const int lane = threadIdx.x;
    const int b = blockIdx.x >> 4, bi = blockIdx.x & 15;

    for (int i = lane; i < NW * 64; i += 64)
        raw[i] = dirs[(size_t)(b * 16 + bi) * (NW * 64) + i];
    for (int k = lane; k < TT; k += 64) {
        float4 t4 = ((const float4*)targs)[(size_t)b * TT + k];
        qsh[k] = make_float2(t4.x, t4.y);
    }
    {
        float4 p4 = ((const float4*)preds)[(size_t)b * TT + bi * 64 + lane];
        psh[lane] = make_float2(p4.x, p4.y);
    }
    __syncthreads();
    for (int i = lane; i < 64 * 32; i += 64) {
        const int rr = i >> 5, u = i & 31;
        const int o  = ((bi & 1) << 5) + (rr >> 1);
        const int T0 = u + (o >> 5), sh = o & 31;
        uint2 A  = raw[T0 * 64 + rr];
        uint2 Bv = raw[(T0 + 1) * 64 + rr];
        nebit[rr][u] = sh ? ((A.x >> sh) | (Bv.x << (32 - sh))) : A.x;
        dgbit[rr][u] = sh ? ((A.y >> sh) | (Bv.y << (32 - sh))) : A.y;
    }
    __syncthreads();
    {                              // per-row prev-nonzero-word table (row=lane)
        int p = -1;
        for (int u = 0; u < 32; ++u) {
            if (nebit[lane][u] != 0u) p = u;
            prevnz[lane][u] = (short)p;
        }
    }

    // entry col for this band: fold of exitc over bands 15..bi+1 (broadcast
    // same-address loads, <=15 dependent L2 hits)
    int j = TT - 1;
    for (int k = 15; k > bi; --k)
        j = exitc[((size_t)(b * 16 + k) << 10) + j];
    __syncthreads();

    // wave-redundant replay; lane 0 records <=32-col span chunks
    int nrec = 0;
    for (int rr = 63; rr >= 0; --rr) {
        int j2;
        if (bi == 0 && rr == 0) j2 = 0;
        else {
            const int u = j >> 5, m = j & 31;
            const unsigned wv = nebit[rr][u] << (31 - m);
            if (wv != 0u) j2 = (u << 5) + m - __builtin_clz(wv);
            else {
                const int u2 = (u > 0) ? (int)prevnz[rr][u - 1] : -1;
                j2 = (u2 < 0) ? 0 : ((u2 << 5) + 31 - __builtin_clz(nebit[rr][u2]));
            }
        }
        int c = j;
        for (;;) {
            int cl = (c - 31 > j2) ? (c - 31) : j2;
            if (lane == 0)
                recs[nrec] = ((unsigned)rr << 20) | ((unsigned)cl << 10) | (unsigned)c;
            ++nrec;
            if (cl == j2) break;
            c = cl - 1;
        }
        if (bi == 0 && rr == 0) j = 0;
        else {
            const int diag = (int)((dgbit[rr][j2 >> 5] >> (j2 & 31)) & 1u);
            j = j2 - diag;
            if (j < 0) j = 0;   // safety net (unreachable on correct dirs)
        }
    }
    __syncthreads();

    const float sc0 = subcoef[0], sc1 = subcoef[1];
    float acc = 0.0f;
    for (int k = lane; k < nrec; k += 64) {
        unsigned rec = recs[k];
        int rr = (int)(rec >> 20), cl = (int)((rec >> 10) & 1023u), ch = (int)(rec & 1023u);
        float2 p = psh[rr];
        for (int c = cl; c <= ch; ++c) {
            float2 q = qsh[c];
            acc += fabsf(p.x - q.x) * sc0 + fabsf(p.y - q.y) * sc1;
        }
    }
    for (int o = 32; o; o >>= 1) acc += __shfl_down(acc, o);
    if (lane == 0) atomicAdd(out, acc);
}

extern "C" void kernel_launch(void* const* d_in, const int* in_sizes, int n_in,
                              void* d_out, int out_size, void* d_ws, size_t ws_size,
                              hipStream_t stream)
{
    const float* preds   = (const float*)d_in[0];
    const float* targs   = (const float*)d_in[1];
    const float* subcoef = (const float*)d_in[2];
    float* out = (float*)d_out;

    const int B = in_sizes[0] / (TT * 4);

    const size_t dirsBytes = (size_t)B * 16 * NW * 64 * sizeof(uint2);        // ~17.8 MB
    uint2* dirs = (uint2*)d_ws;
    unsigned short* exitc = (unsigned short*)((char*)d_ws + dirsBytes);       // 2 MB

    hipMemsetAsync(out, 0, sizeof(float), stream);
    dtw_forward<<<dim3(B), dim3(512), 0, stream>>>(preds, targs, dirs);
    dtw_exits<<<dim3(B * 16), dim3(1024), 0, stream>>>(dirs, exitc);
    dtw_loss<<<dim3(B * 16), dim3(64), 0, stream>>>(preds, targs, subcoef, dirs, exitc, out);
}